// Round 1
// baseline (205.884 us; speedup 1.0000x reference)
//
#include <hip/hip_runtime.h>
#include <hip/hip_bf16.h>

// Problem constants: h[B,G,D], W[G,D,K], out[B,G,K]
#define Gn   100
#define Bn   256
#define Dn   768
#define Kn   128
#define LDP  40   // padded LDS leading dim in shorts (32 + 8): breaks 16-way bank aliasing

typedef __attribute__((ext_vector_type(8))) short short8;
typedef __attribute__((ext_vector_type(4))) float f32x4;

__device__ inline unsigned short f2b(float f) {
  // fp32 -> bf16 round-to-nearest-even (inputs are finite normals)
  union { float f; unsigned u; } v; v.f = f;
  unsigned r = v.u + 0x7FFFu + ((v.u >> 16) & 1u);
  return (unsigned short)(r >> 16);
}

// ---- h row inverse norms: one wave per (b,g) row of 768 contiguous floats ----
__global__ __launch_bounds__(256) void hnorm_kernel(const float* __restrict__ h,
                                                    float* __restrict__ hinv) {
  const int row  = blockIdx.x * 4 + (threadIdx.x >> 6);   // 0 .. B*G-1
  const int lane = threadIdx.x & 63;
  const float4* p = (const float4*)(h + (size_t)row * Dn);
  float ssq = 0.f;
#pragma unroll
  for (int j = 0; j < 3; ++j) {             // 192 float4 per row, 64 lanes
    float4 v = p[j * 64 + lane];
    ssq += v.x*v.x + v.y*v.y + v.z*v.z + v.w*v.w;
  }
#pragma unroll
  for (int off = 32; off > 0; off >>= 1) ssq += __shfl_down(ssq, off);
  if (lane == 0) hinv[row] = 1.0f / fmaxf(sqrtf(ssq), 1e-12f);
}

// ---- W column sum-of-squares over D (strided), coalesced across k ----
// grid (G, 4), block 256: thread = (k, dh); each does 96 d-steps; atomicAdd combine.
__global__ __launch_bounds__(256) void wssq_kernel(const float* __restrict__ W,
                                                   float* __restrict__ wssq) {
  const int g  = blockIdx.x;
  const int s  = blockIdx.y;                 // d-slab 0..3
  const int t  = threadIdx.x;
  const int k  = t & 127;
  const int dh = t >> 7;                     // 0..1
  const float* p = W + (size_t)g * (Dn * Kn) + (size_t)(s * 192 + dh * 96) * Kn + k;
  float ssq = 0.f;
#pragma unroll 8
  for (int i = 0; i < 96; ++i) { float v = p[(size_t)i * Kn]; ssq += v * v; }
  atomicAdd(&wssq[g * Kn + k], ssq);
}

// ---- grouped GEMM: 64x64 tile / block, 4 waves (2x2), mfma_f32_16x16x32_bf16 ----
// grid (Mtiles=4, Ntiles=2, G=100), block 256.
__global__ __launch_bounds__(256) void gemm_kernel(
    const float* __restrict__ h, const float* __restrict__ W,
    const float* __restrict__ hinv, const float* __restrict__ wssq,
    float* __restrict__ out) {
  const int g    = blockIdx.z;
  const int mt   = blockIdx.x;               // 0..3 (rows of 64)
  const int nt   = blockIdx.y;               // 0..1 (cols of 64)
  const int t    = threadIdx.x;
  const int lane = t & 63;
  const int wave = t >> 6;
  const int wm   = wave >> 1, wn = wave & 1; // 2x2 wave grid, 32x32 each

  __shared__ short Alds[64 * LDP];           // [m][k] bf16, k-contiguous
  __shared__ short Blds[64 * LDP];           // [n][k] bf16 (W tile transposed)

  f32x4 acc00 = {0.f,0.f,0.f,0.f};
  f32x4 acc01 = acc00, acc10 = acc00, acc11 = acc00;

  // A staging: thread -> (row ar, 8 contiguous d at ac); 2x float4 per chunk
  const int ar = t >> 2;
  const int ac = (t & 3) * 8;
  const float* aptr = h + ((size_t)(mt * 64 + ar) * Gn + g) * Dn + ac;
  // B staging: thread -> (col bk, 8 strided d at bd); coalesced across lanes (k-contig)
  const int bk = t & 63;
  const int bd = (t >> 6) * 8;
  const float* bptr = W + (size_t)g * (Dn * Kn) + (size_t)bd * Kn + nt * 64 + bk;

  const int quad = lane >> 4;
  const int koff = quad * 8;                 // fragment k-offset (A/B: k = quad*8 + j)
  const int l15  = lane & 15;
  const int m0   = wm * 32 + l15;
  const int n0   = wn * 32 + l15;

  for (int kc = 0; kc < 24; ++kc) {
    const int d0 = kc * 32;
    // issue global loads before the barrier (overlap with prior MFMA)
    float4 a0 = *(const float4*)(aptr + d0);
    float4 a1 = *(const float4*)(aptr + d0 + 4);
    float bv[8];
#pragma unroll
    for (int i = 0; i < 8; ++i) bv[i] = bptr[(size_t)(d0 + i) * Kn];

    if (kc) __syncthreads();                 // prior iter done reading LDS

    union { unsigned short us[8]; short8 v; } pa;
    pa.us[0]=f2b(a0.x); pa.us[1]=f2b(a0.y); pa.us[2]=f2b(a0.z); pa.us[3]=f2b(a0.w);
    pa.us[4]=f2b(a1.x); pa.us[5]=f2b(a1.y); pa.us[6]=f2b(a1.z); pa.us[7]=f2b(a1.w);
    *(short8*)&Alds[ar * LDP + ac] = pa.v;

    union { unsigned short us[8]; short8 v; } pb;
#pragma unroll
    for (int i = 0; i < 8; ++i) pb.us[i] = f2b(bv[i]);
    *(short8*)&Blds[bk * LDP + bd] = pb.v;

    __syncthreads();

    short8 af0 = *(const short8*)&Alds[m0 * LDP + koff];
    short8 af1 = *(const short8*)&Alds[(m0 + 16) * LDP + koff];
    short8 bf0 = *(const short8*)&Blds[n0 * LDP + koff];
    short8 bf1 = *(const short8*)&Blds[(n0 + 16) * LDP + koff];

    acc00 = __builtin_amdgcn_mfma_f32_16x16x32_bf16(af0, bf0, acc00, 0, 0, 0);
    acc01 = __builtin_amdgcn_mfma_f32_16x16x32_bf16(af0, bf1, acc01, 0, 0, 0);
    acc10 = __builtin_amdgcn_mfma_f32_16x16x32_bf16(af1, bf0, acc10, 0, 0, 0);
    acc11 = __builtin_amdgcn_mfma_f32_16x16x32_bf16(af1, bf1, acc11, 0, 0, 0);
  }

  // epilogue: scale by hinv[b] * (1/max(sqrt(wssq),eps)), C/D layout:
  // col = lane&15, row = quad*4 + reg
  const int gk0 = g * Kn + nt * 64;
  const float wi0 = 1.0f / fmaxf(sqrtf(wssq[gk0 + n0]), 1e-12f);
  const float wi1 = 1.0f / fmaxf(sqrtf(wssq[gk0 + n0 + 16]), 1e-12f);

#pragma unroll
  for (int mi = 0; mi < 2; ++mi) {
#pragma unroll
    for (int r = 0; r < 4; ++r) {
      const int row = mt * 64 + wm * 32 + mi * 16 + quad * 4 + r;
      const float hs = hinv[(size_t)row * Gn + g];
      const float v0 = (mi ? acc10[r] : acc00[r]) * hs * wi0;
      const float v1 = (mi ? acc11[r] : acc01[r]) * hs * wi1;
      const size_t ob = ((size_t)row * Gn + g) * Kn + nt * 64;
      out[ob + wn * 32 + l15]      = v0;
      out[ob + wn * 32 + l15 + 16] = v1;
    }
  }
}

extern "C" void kernel_launch(void* const* d_in, const int* in_sizes, int n_in,
                              void* d_out, int out_size, void* d_ws, size_t ws_size,
                              hipStream_t stream) {
  const float* h = (const float*)d_in[0];          // [B,G,D]
  const float* W = (const float*)d_in[1];          // [G,D,K]
  float* out = (float*)d_out;                      // [B,G,K]

  // workspace: hinv [B*G] floats, then wssq [G*K] floats (~154 KB)
  float* hinv = (float*)d_ws;
  float* wssq = hinv + (size_t)Bn * Gn;

  hipMemsetAsync((void*)wssq, 0, (size_t)Gn * Kn * sizeof(float), stream);
  hipLaunchKernelGGL(hnorm_kernel, dim3((Bn * Gn) / 4), dim3(256), 0, stream, h, hinv);
  hipLaunchKernelGGL(wssq_kernel, dim3(Gn, 4), dim3(256), 0, stream, W, wssq);
  hipLaunchKernelGGL(gemm_kernel, dim3(4, 2, Gn), dim3(256), 0, stream,
                     h, W, hinv, wssq, out);
}

// Round 2
// 171.883 us; speedup vs baseline: 1.1978x; 1.1978x over previous
//
#include <hip/hip_runtime.h>

// Problem constants: h[B,G,D], W[G,D,K], out[B,G,K]
#define Gn   100
#define Bn   256
#define Dn   768
#define Kn   128
#define LDP  40   // padded LDS leading dim in shorts (32+8); 80 B row stride (16B-aligned)

typedef __attribute__((ext_vector_type(8))) short short8;
typedef __attribute__((ext_vector_type(4))) float f32x4;

__device__ inline unsigned short f2b(float f) {
  // fp32 -> bf16 round-to-nearest-even (inputs are finite normals)
  union { float f; unsigned u; } v; v.f = f;
  unsigned r = v.u + 0x7FFFu + ((v.u >> 16) & 1u);
  return (unsigned short)(r >> 16);
}

// Fully fused: grouped GEMM with L2 norms computed in-flight.
// 64x64 tile / block, 4 waves (2x2), mfma_f32_16x16x32_bf16, K-loop = full D.
// grid (Mtiles=4, Ntiles=2, G=100), block 256.
// Norms: each block's K-loop touches all 768 d for its 64 rows / 64 cols, so
// row-ssq (h) and col-ssq (W) are accumulated from the fp32 values during
// staging (before bf16 cvt), block-reduced through LDS, applied in epilogue.
__global__ __launch_bounds__(256) void groupfc_kernel(
    const float* __restrict__ h, const float* __restrict__ W,
    float* __restrict__ out) {
  const int g    = blockIdx.z;
  const int mt   = blockIdx.x;               // 0..3 (rows of 64)
  const int nt   = blockIdx.y;               // 0..1 (cols of 64)
  const int t    = threadIdx.x;
  const int lane = t & 63;
  const int wave = t >> 6;
  const int wm   = wave >> 1, wn = wave & 1; // 2x2 wave grid, 32x32 each

  __shared__ short Alds[2][64 * LDP];        // [m][k] bf16, double-buffered
  __shared__ short Blds[2][64 * LDP];        // [n][k] bf16 (W tile transposed)
  __shared__ float AssqL[64];                // per-row  sum(h^2)  (full D)
  __shared__ float BssqL[4][64];             // per-col  sum(W^2)  partials per wave

  f32x4 acc00 = {0.f,0.f,0.f,0.f};
  f32x4 acc01 = acc00, acc10 = acc00, acc11 = acc00;

  // A staging: thread -> (row ar, 8 contiguous d at ac)
  const int ar = t >> 2;
  const int ac = (t & 3) * 8;
  const float* aptr = h + ((size_t)(mt * 64 + ar) * Gn + g) * Dn + ac;
  // B staging: thread -> (col bk, 8 d starting at bd); coalesced across lanes (k-contig)
  const int bk = t & 63;
  const int bd = (t >> 6) * 8;
  const float* bptr = W + (size_t)g * (Dn * Kn) + (size_t)bd * Kn + nt * 64 + bk;

  const int quad = lane >> 4;
  const int koff = quad * 8;                 // fragment k-offset (A/B: k = quad*8 + j)
  const int l15  = lane & 15;
  const int m0   = wm * 32 + l15;
  const int n0   = wn * 32 + l15;

  float assq = 0.f, bssq = 0.f;

  // ---- prologue: load chunk 0 into registers ----
  float4 a0 = *(const float4*)(aptr);
  float4 a1 = *(const float4*)(aptr + 4);
  float bv[8];
#pragma unroll
  for (int i = 0; i < 8; ++i) bv[i] = bptr[(size_t)i * Kn];

  for (int kc = 0; kc < 24; ++kc) {
    // prefetch chunk kc+1 into registers (latency overlapped with everything below)
    float4 na0, na1;
    float nbv[8];
    if (kc < 23) {
      const int d0 = (kc + 1) * 32;
      na0 = *(const float4*)(aptr + d0);
      na1 = *(const float4*)(aptr + d0 + 4);
#pragma unroll
      for (int i = 0; i < 8; ++i) nbv[i] = bptr[(size_t)(d0 + i) * Kn];
    }

    // stage current chunk into LDS buf[kc&1], accumulating fp32 ssq
    assq += a0.x*a0.x + a0.y*a0.y + a0.z*a0.z + a0.w*a0.w
          + a1.x*a1.x + a1.y*a1.y + a1.z*a1.z + a1.w*a1.w;
    union { unsigned short us[8]; short8 v; } pa;
    pa.us[0]=f2b(a0.x); pa.us[1]=f2b(a0.y); pa.us[2]=f2b(a0.z); pa.us[3]=f2b(a0.w);
    pa.us[4]=f2b(a1.x); pa.us[5]=f2b(a1.y); pa.us[6]=f2b(a1.z); pa.us[7]=f2b(a1.w);
    *(short8*)&Alds[kc & 1][ar * LDP + ac] = pa.v;

    union { unsigned short us[8]; short8 v; } pb;
#pragma unroll
    for (int i = 0; i < 8; ++i) { bssq += bv[i] * bv[i]; pb.us[i] = f2b(bv[i]); }
    *(short8*)&Blds[kc & 1][bk * LDP + bd] = pb.v;

    __syncthreads();                         // buf[kc&1] ready (single barrier per iter)

    short8 af0 = *(const short8*)&Alds[kc & 1][m0 * LDP + koff];
    short8 af1 = *(const short8*)&Alds[kc & 1][(m0 + 16) * LDP + koff];
    short8 bf0 = *(const short8*)&Blds[kc & 1][n0 * LDP + koff];
    short8 bf1 = *(const short8*)&Blds[kc & 1][(n0 + 16) * LDP + koff];

    acc00 = __builtin_amdgcn_mfma_f32_16x16x32_bf16(af0, bf0, acc00, 0, 0, 0);
    acc01 = __builtin_amdgcn_mfma_f32_16x16x32_bf16(af0, bf1, acc01, 0, 0, 0);
    acc10 = __builtin_amdgcn_mfma_f32_16x16x32_bf16(af1, bf0, acc10, 0, 0, 0);
    acc11 = __builtin_amdgcn_mfma_f32_16x16x32_bf16(af1, bf1, acc11, 0, 0, 0);

    a0 = na0; a1 = na1;
#pragma unroll
    for (int i = 0; i < 8; ++i) bv[i] = nbv[i];
  }

  // ---- block-reduce the norms ----
  // A: 4 threads (t&3) share row ar; butterfly then one writes.
  assq += __shfl_xor(assq, 1);
  assq += __shfl_xor(assq, 2);
  if ((t & 3) == 0) AssqL[ar] = assq;
  // B: 4 waves share col bk.
  BssqL[wave][bk] = bssq;
  __syncthreads();

  // ---- epilogue: scale by 1/max(||h_row||,eps) * 1/max(||w_col||,eps) ----
  // C/D layout: col = lane&15, row = quad*4 + reg
  const float ws0 = BssqL[0][n0] + BssqL[1][n0] + BssqL[2][n0] + BssqL[3][n0];
  const float ws1 = BssqL[0][n0+16] + BssqL[1][n0+16] + BssqL[2][n0+16] + BssqL[3][n0+16];
  const float wi0 = 1.0f / fmaxf(sqrtf(ws0), 1e-12f);
  const float wi1 = 1.0f / fmaxf(sqrtf(ws1), 1e-12f);

#pragma unroll
  for (int mi = 0; mi < 2; ++mi) {
#pragma unroll
    for (int r = 0; r < 4; ++r) {
      const int lr  = wm * 32 + mi * 16 + quad * 4 + r;   // local row in tile
      const float hs = 1.0f / fmaxf(sqrtf(AssqL[lr]), 1e-12f);
      const float v0 = (mi ? acc10[r] : acc00[r]) * hs * wi0;
      const float v1 = (mi ? acc11[r] : acc01[r]) * hs * wi1;
      const int row = mt * 64 + lr;
      const size_t ob = ((size_t)row * Gn + g) * Kn + nt * 64;
      out[ob + wn * 32 + l15]      = v0;
      out[ob + wn * 32 + l15 + 16] = v1;
    }
  }
}

extern "C" void kernel_launch(void* const* d_in, const int* in_sizes, int n_in,
                              void* d_out, int out_size, void* d_ws, size_t ws_size,
                              hipStream_t stream) {
  const float* h = (const float*)d_in[0];          // [B,G,D]
  const float* W = (const float*)d_in[1];          // [G,D,K]
  float* out = (float*)d_out;                      // [B,G,K]
  hipLaunchKernelGGL(groupfc_kernel, dim3(4, 2, Gn), dim3(256), 0, stream, h, W, out);
}